// Round 10
// baseline (791.435 us; speedup 1.0000x reference)
//
#include <hip/hip_runtime.h>

#define NSEQ 256
#define NRES 1024
#define CM   256
#define CC   32
#define CZ   128
#define EPS  1e-5f
#define SROW (NRES * CM)   // stride between s-rows of x for fixed r
#define XST  68            // xp row stride (floats): 64 data + 4 pad -> dense banks

typedef float f4v __attribute__((ext_vector_type(4)));
typedef __attribute__((ext_vector_type(8))) short short8;   // bf16x8 MFMA frag
typedef __attribute__((ext_vector_type(4))) float f32x4;    // MFMA acc
typedef unsigned int u32;

__device__ __forceinline__ float trunc_bf16(float f) {
    return __uint_as_float(__float_as_uint(f) & 0xffff0000u);
}
__device__ __forceinline__ u32 pk_bf16(float a, float b) {   // low=a, high=b
    return (__float_as_uint(b) & 0xffff0000u) | (__float_as_uint(a) >> 16);
}

// ===================== Kernel S: K1/K2 + B-fragment-arranged bf16x2 weights =====================
// (verbatim from round 8 — validated end-to-end)
__global__ void opm_setup(const float* __restrict__ nw,
                          const float* __restrict__ nb,
                          const float* __restrict__ w_ab,
                          const float* __restrict__ b_ab,
                          float* __restrict__ k12,
                          unsigned short* __restrict__ wb_su)
{
    __shared__ float wls[CM * CC];
    const int t = threadIdx.x;          // 256 threads, t == m
    const float nwm = nw[t];
    #pragma unroll
    for (int c = 0; c < CC; ++c)
        wls[t * CC + c] = nwm * w_ab[c * CM + t];
    __syncthreads();
    if (t < CC) {
        float k1 = 0.f, k2 = 0.f;
        for (int m = 0; m < CM; ++m) {
            k1 += wls[m * CC + t];
            k2 = fmaf(nb[m], w_ab[t * CM + m], k2);
        }
        k12[t]      = k1;
        k12[CC + t] = k2 + b_ab[t];
    }
    for (int e = t; e < 16384; e += 256) {
        const int j     = e & 7;
        const int l     = (e >> 3) & 63;
        const int split = (e >> 9) & 1;
        const int nt    = (e >> 10) & 1;
        const int kk    = e >> 11;
        const int m = (kk << 5) + ((l >> 4) << 3) + j;
        const int c = (nt << 4) + (l & 15);
        const float w  = wls[m * CC + c];
        const float w1 = trunc_bf16(w);
        const float v  = split ? (w - w1) : w;
        wb_su[e] = (unsigned short)(__float_as_uint(v) >> 16);
    }
}

// ===================== Kernel A: MFMA, 256-B burst staging, 4 passes =====================
// One block per residue r. 256 threads = 4 waves, 2 blocks/CU (70 KB LDS).
// Thread t owns s-row t. Per chunk (MCH=64, 4 chunks): thread reads a 256-B
// CONTIGUOUS burst of its row (16 dwordx4 back-to-back -> DRAM page opened
// once per 256 B, vs 128 B x 8 passes before), writes f32 to xp[t][0..64)
// (stride 68: burst writes AND mfma-side reads land 8-deep dense, no
// conflicts), accumulates exact per-thread stats. Next-chunk loads issue
// before the barrier and fly across the MFMA phase. B-fragments load from
// global per chunk (L2-resident 32 KB; frees the old 32-KB wbl LDS).
// MFMA phase per chunk: 2 k-steps x 4 tiles x {2 f32 b128 reads -> in-lane
// bf16x2 convert -> 6 mfma_16x16x32}. acc/fragment math identical to the
// validated round-8/9 kernel. Epilogue P2/P3/P4 verbatim (aB/scr overlay xp).
__launch_bounds__(256, 2)
__global__ void opm_compute(const float* __restrict__ msa,
                            const u32*  __restrict__ wb_g,
                            const float* __restrict__ k12,
                            const float* __restrict__ w_out,
                            const float* __restrict__ b_out,
                            float* __restrict__ pre_out)
{
    __shared__ float xp[NSEQ * XST];   // 68 KB: f32 chunk [256][68]; aB+scr after
    __shared__ float st[512];          // mu [0..255], rstd [256..511]

    const int tid = threadIdx.x;
    const int r   = blockIdx.x;
    const int w   = tid >> 6;           // wave 0..3
    const int l   = tid & 63;
    const int lr  = l & 15;             // row-in-tile / C-col
    const int lk  = l >> 4;             // k-group 0..3

    const float* xr = msa + (size_t)tid * SROW + (size_t)r * CM;  // this thread's s-row

    f32x4 acc[4][2];
    #pragma unroll
    for (int mt = 0; mt < 4; ++mt) { acc[mt][0] = (f32x4)0.f; acc[mt][1] = (f32x4)0.f; }
    float psum = 0.f, pssq = 0.f;

    // prologue: chunk 0 burst (256 B contiguous per thread)
    float4 nx[16];
    #pragma unroll
    for (int i = 0; i < 16; ++i)
        nx[i] = *(const float4*)(xr + (i << 2));

    #pragma unroll 1
    for (int c = 0; c < 4; ++c) {
        if (c) __syncthreads();        // (A) chunk c-1 readers done
        // stage burst -> xp (dense bank pattern), exact stats from regs
        #pragma unroll
        for (int i = 0; i < 16; ++i) {
            *(float4*)&xp[tid * XST + (i << 2)] = nx[i];
            psum += (nx[i].x + nx[i].y) + (nx[i].z + nx[i].w);
            pssq  = fmaf(nx[i].x, nx[i].x, fmaf(nx[i].y, nx[i].y,
                    fmaf(nx[i].z, nx[i].z, fmaf(nx[i].w, nx[i].w, pssq))));
        }
        // B-frags for this chunk's 2 k-steps (L2-resident; issued before nx)
        short8 B[2][2][2];             // [kk2][nt][sp]
        #pragma unroll
        for (int kk2 = 0; kk2 < 2; ++kk2) {
            const int kk = (c << 1) + kk2;
            #pragma unroll
            for (int nt = 0; nt < 2; ++nt)
                #pragma unroll
                for (int sp = 0; sp < 2; ++sp) {
                    const int fb = ((((kk << 1) + nt) << 1) + sp) * 256 + (l << 2);
                    B[kk2][nt][sp] = __builtin_bit_cast(short8, *(const f4v*)&wb_g[fb]);
                }
        }
        // issue next-chunk burst; stays in flight across the MFMA phase
        if (c < 3) {
            #pragma unroll
            for (int i = 0; i < 16; ++i)
                nx[i] = *(const float4*)(xr + ((c + 1) << 6) + (i << 2));
        }
        __syncthreads();               // (B) chunk c visible
        // MFMA phase: 2 k-steps x 4 tiles
        #pragma unroll
        for (int kk2 = 0; kk2 < 2; ++kk2) {
            #pragma unroll
            for (int mt = 0; mt < 4; ++mt) {
                const float* ap = &xp[((w << 6) + (mt << 4) + lr) * XST + (kk2 << 5) + (lk << 3)];
                const float4 pa = *(const float4*)ap;
                const float4 pb = *(const float4*)(ap + 4);
                uint4 u1, u2;
                u1.x = pk_bf16(pa.x, pa.y); u1.y = pk_bf16(pa.z, pa.w);
                u1.z = pk_bf16(pb.x, pb.y); u1.w = pk_bf16(pb.z, pb.w);
                u2.x = pk_bf16(pa.x - trunc_bf16(pa.x), pa.y - trunc_bf16(pa.y));
                u2.y = pk_bf16(pa.z - trunc_bf16(pa.z), pa.w - trunc_bf16(pa.w));
                u2.z = pk_bf16(pb.x - trunc_bf16(pb.x), pb.y - trunc_bf16(pb.y));
                u2.w = pk_bf16(pb.z - trunc_bf16(pb.z), pb.w - trunc_bf16(pb.w));
                const short8 A1 = __builtin_bit_cast(short8, u1);
                const short8 A2 = __builtin_bit_cast(short8, u2);
                acc[mt][0] = __builtin_amdgcn_mfma_f32_16x16x32_bf16(A1, B[kk2][0][0], acc[mt][0], 0, 0, 0);
                acc[mt][1] = __builtin_amdgcn_mfma_f32_16x16x32_bf16(A1, B[kk2][1][0], acc[mt][1], 0, 0, 0);
                acc[mt][0] = __builtin_amdgcn_mfma_f32_16x16x32_bf16(A1, B[kk2][0][1], acc[mt][0], 0, 0, 0);
                acc[mt][1] = __builtin_amdgcn_mfma_f32_16x16x32_bf16(A1, B[kk2][1][1], acc[mt][1], 0, 0, 0);
                acc[mt][0] = __builtin_amdgcn_mfma_f32_16x16x32_bf16(A2, B[kk2][0][0], acc[mt][0], 0, 0, 0);
                acc[mt][1] = __builtin_amdgcn_mfma_f32_16x16x32_bf16(A2, B[kk2][1][0], acc[mt][1], 0, 0, 0);
            }
        }
    }

    // ---- stats: exact per-thread full-row; publish directly ----
    {
        const float mu  = psum * (1.f / CM);
        const float var = pssq * (1.f / CM) - mu * mu;
        st[tid]       = mu;
        st[256 + tid] = 1.f / sqrtf(var + EPS);
    }
    __syncthreads();   // (B') all MFMA xp-reads done; stats visible

    // ---------------- P2: LN-fold -> a[s][32] at xp[0..8191], XOR-swizzled ----------------
    float* aB = xp;
    {
        const int cl = lr;
        const float k1_0 = k12[cl],      k1_1 = k12[16 + cl];
        const float k2_0 = k12[CC + cl], k2_1 = k12[CC + 16 + cl];
        #pragma unroll
        for (int mt = 0; mt < 4; ++mt) {
            #pragma unroll
            for (int rg = 0; rg < 4; ++rg) {
                const int s = (w << 6) + (mt << 4) + (lk << 2) + rg;
                const float mu = st[s], rs = st[256 + s];
                const float a0 = fmaf(rs, acc[mt][0][rg] - mu * k1_0, k2_0);
                const float a1 = fmaf(rs, acc[mt][1][rg] - mu * k1_1, k2_1);
                const int sw = s & 7;
                aB[s * CC + (((cl >> 2) ^ sw) << 2) + (cl & 3)]       = a0;
                aB[s * CC + ((((cl >> 2) + 4) ^ sw) << 2) + (cl & 3)] = a1;
            }
        }
    }
    __syncthreads();   // (C) a complete

    // ---------------- P3: o = A^T A / NSEQ, split-K(4) x 4x4 tiles ----------------
    float* scr = xp + 8192;            // 4352 floats, disjoint from aB
    const int grp = w;                 // s-slice 64*grp .. +63
    const int xs_ = (tid >> 3) & 7;    // row f4-slot
    const int ys_ = tid & 7;           // col f4-slot
    float4 pr0 = {0,0,0,0}, pr1 = {0,0,0,0}, pr2 = {0,0,0,0}, pr3 = {0,0,0,0};
    #pragma unroll 4
    for (int si = 0; si < 64; ++si) {
        const int s  = (grp << 6) + si;
        const int sw = s & 7;
        const float4 ax = *(const float4*)&aB[s * CC + ((xs_ ^ sw) << 2)];
        const float4 ay = *(const float4*)&aB[s * CC + ((ys_ ^ sw) << 2)];
        pr0.x = fmaf(ax.x, ay.x, pr0.x); pr0.y = fmaf(ax.x, ay.y, pr0.y);
        pr0.z = fmaf(ax.x, ay.z, pr0.z); pr0.w = fmaf(ax.x, ay.w, pr0.w);
        pr1.x = fmaf(ax.y, ay.x, pr1.x); pr1.y = fmaf(ax.y, ay.y, pr1.y);
        pr1.z = fmaf(ax.y, ay.z, pr1.z); pr1.w = fmaf(ax.y, ay.w, pr1.w);
        pr2.x = fmaf(ax.z, ay.x, pr2.x); pr2.y = fmaf(ax.z, ay.y, pr2.y);
        pr2.z = fmaf(ax.z, ay.z, pr2.z); pr2.w = fmaf(ax.z, ay.w, pr2.w);
        pr3.x = fmaf(ax.w, ay.x, pr3.x); pr3.y = fmaf(ax.w, ay.y, pr3.y);
        pr3.z = fmaf(ax.w, ay.z, pr3.z); pr3.w = fmaf(ax.w, ay.w, pr3.w);
    }
    {
        float* pb = &scr[(grp << 10) + ((xs_ << 2) * CC) + (ys_ << 2)];
        *(float4*)&pb[0 * CC] = pr0;
        *(float4*)&pb[1 * CC] = pr1;
        *(float4*)&pb[2 * CC] = pr2;
        *(float4*)&pb[3 * CC] = pr3;
    }
    __syncthreads();   // (D) partials visible
    {
        const float inv_s = 1.f / NSEQ;
        float4 a4 = *(const float4*)&scr[(tid << 2)];
        const float4 b1 = *(const float4*)&scr[1024 + (tid << 2)];
        const float4 b2 = *(const float4*)&scr[2048 + (tid << 2)];
        const float4 b3 = *(const float4*)&scr[3072 + (tid << 2)];
        a4.x = (a4.x + b1.x + b2.x + b3.x) * inv_s;
        a4.y = (a4.y + b1.y + b2.y + b3.y) * inv_s;
        a4.z = (a4.z + b1.z + b2.z + b3.z) * inv_s;
        a4.w = (a4.w + b1.w + b2.w + b3.w) * inv_s;
        *(float4*)&scr[tid << 2] = a4;
    }
    __syncthreads();   // (E) o visible

    // ---------------- P4: pre[z] = o . w_out[z] + b_out[z] ----------------
    {
        const int z    = tid & 127;
        const int half = tid >> 7;
        const float* wrow = w_out + (size_t)z * (CC * CC) + half * 512;
        const float* op   = &scr[half * 512];
        float po = 0.f;
        #pragma unroll 8
        for (int k = 0; k < 512; k += 4) {
            const float4 o4 = *(const float4*)&op[k];
            const float4 w4 = *(const float4*)&wrow[k];
            po = fmaf(o4.x, w4.x, fmaf(o4.y, w4.y, fmaf(o4.z, w4.z, fmaf(o4.w, w4.w, po))));
        }
        scr[4096 + (half << 7) + z] = po;
    }
    __syncthreads();   // (F)
    if (tid < CZ)
        pre_out[(size_t)r * CZ + tid] = scr[4096 + tid] + scr[4096 + CZ + tid] + b_out[tid];
}

// ===================== Kernel B: broadcast pre over 1024 rows =====================
__launch_bounds__(256, 8)
__global__ void opm_bcast(const float* __restrict__ pre,
                          float* __restrict__ out)
{
    const int bid = blockIdx.x;
    const int r   = bid >> 3;                 // 0..1023
    const int jb  = bid & 7;                  // 128-row slab within the r-plane
    const int z4  = threadIdx.x & 31;         // which float4 of the 128-float row
    const int jo  = threadIdx.x >> 5;         // 0..7

    const f4v pv = *((const f4v*)(pre + (size_t)r * CZ) + z4);
    f4v* outp = (f4v*)out + ((size_t)r * NRES + (size_t)jb * 128) * (CZ / 4);
    for (int j0 = 0; j0 < 128; j0 += 8)
        __builtin_nontemporal_store(pv, &outp[(size_t)(j0 + jo) * (CZ / 4) + z4]);
}

extern "C" void kernel_launch(void* const* d_in, const int* in_sizes, int n_in,
                              void* d_out, int out_size, void* d_ws, size_t ws_size,
                              hipStream_t stream) {
    const float* msa   = (const float*)d_in[0];
    const float* nw    = (const float*)d_in[1];
    const float* nb    = (const float*)d_in[2];
    const float* w_ab  = (const float*)d_in[3];
    const float* b_ab  = (const float*)d_in[4];
    const float* w_out = (const float*)d_in[5];
    const float* b_out = (const float*)d_in[6];
    float* out = (float*)d_out;

    float* pre = (float*)d_ws;                           // [0, 131072) floats
    float* k12 = pre + (size_t)NRES * CZ;                // [131072, 131136)
    unsigned short* wb_su = (unsigned short*)(k12 + 64); // 16384 bf16 (32 KB), 16B-aligned

    opm_setup<<<1, 256, 0, stream>>>(nw, nb, w_ab, b_ab, k12, wb_su);
    opm_compute<<<NRES, 256, 0, stream>>>(msa, (const u32*)wb_su, k12, w_out, b_out, pre);
    opm_bcast<<<NRES * 8, 256, 0, stream>>>(pre, out);
}

// Round 11
// 784.219 us; speedup vs baseline: 1.0092x; 1.0092x over previous
//
#include <hip/hip_runtime.h>

#define NSEQ 256
#define NRES 1024
#define CM   256
#define CC   32
#define CZ   128
#define EPS  1e-5f
#define SROW (NRES * CM)   // stride between s-rows of x for fixed r

typedef float f4v __attribute__((ext_vector_type(4)));
typedef __attribute__((ext_vector_type(8))) short short8;   // bf16x8 MFMA frag
typedef __attribute__((ext_vector_type(4))) float f32x4;    // MFMA acc
typedef unsigned int u32;

__device__ __forceinline__ float trunc_bf16(float f) {
    return __uint_as_float(__float_as_uint(f) & 0xffff0000u);
}
__device__ __forceinline__ u32 pk_bf16(float a, float b) {   // low=a, high=b
    return (__float_as_uint(b) & 0xffff0000u) | (__float_as_uint(a) >> 16);
}

// ===================== Kernel S: K1/K2 + B-fragment-arranged bf16x2 weights =====================
// (verbatim from round 8 — validated end-to-end)
__global__ void opm_setup(const float* __restrict__ nw,
                          const float* __restrict__ nb,
                          const float* __restrict__ w_ab,
                          const float* __restrict__ b_ab,
                          float* __restrict__ k12,
                          unsigned short* __restrict__ wb_su)
{
    __shared__ float wls[CM * CC];
    const int t = threadIdx.x;          // 256 threads, t == m
    const float nwm = nw[t];
    #pragma unroll
    for (int c = 0; c < CC; ++c)
        wls[t * CC + c] = nwm * w_ab[c * CM + t];
    __syncthreads();
    if (t < CC) {
        float k1 = 0.f, k2 = 0.f;
        for (int m = 0; m < CM; ++m) {
            k1 += wls[m * CC + t];
            k2 = fmaf(nb[m], w_ab[t * CM + m], k2);
        }
        k12[t]      = k1;
        k12[CC + t] = k2 + b_ab[t];
    }
    for (int e = t; e < 16384; e += 256) {
        const int j     = e & 7;
        const int l     = (e >> 3) & 63;
        const int split = (e >> 9) & 1;
        const int nt    = (e >> 10) & 1;
        const int kk    = e >> 11;
        const int m = (kk << 5) + ((l >> 4) << 3) + j;
        const int c = (nt << 4) + (l & 15);
        const float w  = wls[m * CC + c];
        const float w1 = trunc_bf16(w);
        const float v  = split ? (w - w1) : w;
        wb_su[e] = (unsigned short)(__float_as_uint(v) >> 16);
    }
}

// ===================== Kernel A: direct-to-register MFMA + XCD-contiguous block swizzle =====================
// Identical to the round-9 kernel (best, validated) EXCEPT the one-line T1
// swizzle: r = (bid&7)*128 + bid>>3. Default dispatch round-robins
// consecutive blockIdx across the 8 XCDs, so consecutive r (which read
// ADJACENT 1-KB slices of every 1-MB s-row) land on different XCDs -> ~512
// interleaved 1-KB read streams chip-wide. With the bijective swizzle, XCD x
// serves r in [x*128, x*128+128): its ~64 co-resident blocks read adjacent
// slices, forming contiguous ~64-KB per-s-row streams and XCD-local L2 reuse
// of full lines. nwg=1024 % 8 == 0 -> swizzle is bijective (ERRATA #11 safe).
__launch_bounds__(256, 3)
__global__ void opm_compute(const float* __restrict__ msa,
                            const u32*  __restrict__ wb_g,
                            const float* __restrict__ k12,
                            const float* __restrict__ w_out,
                            const float* __restrict__ b_out,
                            float* __restrict__ pre_out)
{
    __shared__ u32 wbl[8192];          // 32 KB: B-frags during G; a[s][32] after P2
    __shared__ float scr[4352];        // 17 KB: P3 partials/o + pre_part
    __shared__ float st[512];          // mu [0..255], rstd [256..511]

    const int tid = threadIdx.x;
    const int r   = ((blockIdx.x & 7) << 7) | (blockIdx.x >> 3);   // T1 XCD swizzle
    const int w   = tid >> 6;           // wave 0..3
    const int l   = tid & 63;
    const int lr  = l & 15;             // row-in-tile / C-col
    const int lk  = l >> 4;             // k-group 0..3

    const float* xr = msa + (size_t)r * CM;
    size_t rowoff[4];
    #pragma unroll
    for (int mt = 0; mt < 4; ++mt)
        rowoff[mt] = (size_t)((w << 6) + (mt << 4) + lr) * SROW + (lk << 3);

    // stage B-fragments (8192 u32) from global
    #pragma unroll
    for (int k = 0; k < 8; ++k) {
        const int i = (tid + (k << 8)) << 2;
        *(f4v*)&wbl[i] = *(const f4v*)&wb_g[i];
    }

    f32x4 acc[4][2];
    #pragma unroll
    for (int mt = 0; mt < 4; ++mt) { acc[mt][0] = (f32x4)0.f; acc[mt][1] = (f32x4)0.f; }
    float psum[4], pssq[4];
    #pragma unroll
    for (int mt = 0; mt < 4; ++mt) { psum[mt] = 0.f; pssq[mt] = 0.f; }

    // prologue: load kk=0 A-data
    float4 curA[4], curB[4], nxtA[4], nxtB[4];
    #pragma unroll
    for (int mt = 0; mt < 4; ++mt) {
        curA[mt] = *(const float4*)(xr + rowoff[mt]);
        curB[mt] = *(const float4*)(xr + rowoff[mt] + 4);
    }

    __syncthreads();   // wbl visible

    #pragma unroll 1
    for (int kk = 0; kk < 8; ++kk) {
        if (kk < 7) {   // issue next-kk loads first; they fly across the MFMAs
            const int o = (kk + 1) << 5;
            #pragma unroll
            for (int mt = 0; mt < 4; ++mt) {
                nxtA[mt] = *(const float4*)(xr + rowoff[mt] + o);
                nxtB[mt] = *(const float4*)(xr + rowoff[mt] + o + 4);
            }
        }
        // B-frags for this k-step: (nt, split)
        short8 B[2][2];
        #pragma unroll
        for (int nt = 0; nt < 2; ++nt)
            #pragma unroll
            for (int sp = 0; sp < 2; ++sp) {
                const int fb = ((((kk << 1) + nt) << 1) + sp) * 256 + (l << 2);
                B[nt][sp] = __builtin_bit_cast(short8, *(const f4v*)&wbl[fb]);
            }
        #pragma unroll
        for (int mt = 0; mt < 4; ++mt) {
            const float4 pa = curA[mt], pb = curB[mt];
            psum[mt] += ((pa.x + pa.y) + (pa.z + pa.w)) + ((pb.x + pb.y) + (pb.z + pb.w));
            pssq[mt]  = fmaf(pa.x, pa.x, fmaf(pa.y, pa.y, fmaf(pa.z, pa.z, fmaf(pa.w, pa.w, pssq[mt]))));
            pssq[mt]  = fmaf(pb.x, pb.x, fmaf(pb.y, pb.y, fmaf(pb.z, pb.z, fmaf(pb.w, pb.w, pssq[mt]))));
            uint4 u1, u2;
            u1.x = pk_bf16(pa.x, pa.y); u1.y = pk_bf16(pa.z, pa.w);
            u1.z = pk_bf16(pb.x, pb.y); u1.w = pk_bf16(pb.z, pb.w);
            u2.x = pk_bf16(pa.x - trunc_bf16(pa.x), pa.y - trunc_bf16(pa.y));
            u2.y = pk_bf16(pa.z - trunc_bf16(pa.z), pa.w - trunc_bf16(pa.w));
            u2.z = pk_bf16(pb.x - trunc_bf16(pb.x), pb.y - trunc_bf16(pb.y));
            u2.w = pk_bf16(pb.z - trunc_bf16(pb.z), pb.w - trunc_bf16(pb.w));
            const short8 A1 = __builtin_bit_cast(short8, u1);
            const short8 A2 = __builtin_bit_cast(short8, u2);
            acc[mt][0] = __builtin_amdgcn_mfma_f32_16x16x32_bf16(A1, B[0][0], acc[mt][0], 0, 0, 0);
            acc[mt][1] = __builtin_amdgcn_mfma_f32_16x16x32_bf16(A1, B[1][0], acc[mt][1], 0, 0, 0);
            acc[mt][0] = __builtin_amdgcn_mfma_f32_16x16x32_bf16(A1, B[0][1], acc[mt][0], 0, 0, 0);
            acc[mt][1] = __builtin_amdgcn_mfma_f32_16x16x32_bf16(A1, B[1][1], acc[mt][1], 0, 0, 0);
            acc[mt][0] = __builtin_amdgcn_mfma_f32_16x16x32_bf16(A2, B[0][0], acc[mt][0], 0, 0, 0);
            acc[mt][1] = __builtin_amdgcn_mfma_f32_16x16x32_bf16(A2, B[1][0], acc[mt][1], 0, 0, 0);
        }
        if (kk < 7) {
            #pragma unroll
            for (int mt = 0; mt < 4; ++mt) { curA[mt] = nxtA[mt]; curB[mt] = nxtB[mt]; }
        }
    }

    // ---- stats: reduce over the 4 k-groups (lanes l^16, l^32), publish ----
    #pragma unroll
    for (int mt = 0; mt < 4; ++mt) {
        float s1 = psum[mt], s2 = pssq[mt];
        s1 += __shfl_xor(s1, 16); s1 += __shfl_xor(s1, 32);
        s2 += __shfl_xor(s2, 16); s2 += __shfl_xor(s2, 32);
        if (l < 16) {
            const int s = (w << 6) + (mt << 4) + lr;
            const float mu  = s1 * (1.f / CM);
            const float var = s2 * (1.f / CM) - mu * mu;
            st[s]       = mu;
            st[256 + s] = 1.f / sqrtf(var + EPS);
        }
    }
    __syncthreads();   // (B) stats visible; all B-frag reads done

    // ---------------- P2: LN-fold -> a[s][32] in wbl region, XOR-swizzled ----------------
    float* aB = (float*)wbl;
    {
        const int cl = lr;
        const float k1_0 = k12[cl],      k1_1 = k12[16 + cl];
        const float k2_0 = k12[CC + cl], k2_1 = k12[CC + 16 + cl];
        #pragma unroll
        for (int mt = 0; mt < 4; ++mt) {
            #pragma unroll
            for (int rg = 0; rg < 4; ++rg) {
                const int s = (w << 6) + (mt << 4) + (lk << 2) + rg;
                const float mu = st[s], rs = st[256 + s];
                const float a0 = fmaf(rs, acc[mt][0][rg] - mu * k1_0, k2_0);
                const float a1 = fmaf(rs, acc[mt][1][rg] - mu * k1_1, k2_1);
                const int sw = s & 7;
                aB[s * CC + (((cl >> 2) ^ sw) << 2) + (cl & 3)]       = a0;
                aB[s * CC + ((((cl >> 2) + 4) ^ sw) << 2) + (cl & 3)] = a1;
            }
        }
    }
    __syncthreads();   // (C) a complete

    // ---------------- P3: o = A^T A / NSEQ, split-K(4) x 4x4 tiles ----------------
    const int grp = w;                 // s-slice 64*grp .. +63
    const int xs_ = (tid >> 3) & 7;    // row f4-slot
    const int ys_ = tid & 7;           // col f4-slot
    float4 pr0 = {0,0,0,0}, pr1 = {0,0,0,0}, pr2 = {0,0,0,0}, pr3 = {0,0,0,0};
    #pragma unroll 4
    for (int si = 0; si < 64; ++si) {
        const int s  = (grp << 6) + si;
        const int sw = s & 7;
        const float4 ax = *(const float4*)&aB[s * CC + ((xs_ ^ sw) << 2)];
        const float4 ay = *(const float4*)&aB[s * CC + ((ys_ ^ sw) << 2)];
        pr0.x = fmaf(ax.x, ay.x, pr0.x); pr0.y = fmaf(ax.x, ay.y, pr0.y);
        pr0.z = fmaf(ax.x, ay.z, pr0.z); pr0.w = fmaf(ax.x, ay.w, pr0.w);
        pr1.x = fmaf(ax.y, ay.x, pr1.x); pr1.y = fmaf(ax.y, ay.y, pr1.y);
        pr1.z = fmaf(ax.y, ay.z, pr1.z); pr1.w = fmaf(ax.y, ay.w, pr1.w);
        pr2.x = fmaf(ax.z, ay.x, pr2.x); pr2.y = fmaf(ax.z, ay.y, pr2.y);
        pr2.z = fmaf(ax.z, ay.z, pr2.z); pr2.w = fmaf(ax.z, ay.w, pr2.w);
        pr3.x = fmaf(ax.w, ay.x, pr3.x); pr3.y = fmaf(ax.w, ay.y, pr3.y);
        pr3.z = fmaf(ax.w, ay.z, pr3.z); pr3.w = fmaf(ax.w, ay.w, pr3.w);
    }
    {
        float* pb = &scr[(grp << 10) + ((xs_ << 2) * CC) + (ys_ << 2)];
        *(float4*)&pb[0 * CC] = pr0;
        *(float4*)&pb[1 * CC] = pr1;
        *(float4*)&pb[2 * CC] = pr2;
        *(float4*)&pb[3 * CC] = pr3;
    }
    __syncthreads();   // (D) partials visible
    {
        const float inv_s = 1.f / NSEQ;
        float4 a4 = *(const float4*)&scr[(tid << 2)];
        const float4 b1 = *(const float4*)&scr[1024 + (tid << 2)];
        const float4 b2 = *(const float4*)&scr[2048 + (tid << 2)];
        const float4 b3 = *(const float4*)&scr[3072 + (tid << 2)];
        a4.x = (a4.x + b1.x + b2.x + b3.x) * inv_s;
        a4.y = (a4.y + b1.y + b2.y + b3.y) * inv_s;
        a4.z = (a4.z + b1.z + b2.z + b3.z) * inv_s;
        a4.w = (a4.w + b1.w + b2.w + b3.w) * inv_s;
        *(float4*)&scr[tid << 2] = a4;
    }
    __syncthreads();   // (E) o visible

    // ---------------- P4: pre[z] = o . w_out[z] + b_out[z] ----------------
    {
        const int z    = tid & 127;
        const int half = tid >> 7;
        const float* wrow = w_out + (size_t)z * (CC * CC) + half * 512;
        const float* op   = &scr[half * 512];
        float po = 0.f;
        #pragma unroll 8
        for (int k = 0; k < 512; k += 4) {
            const float4 o4 = *(const float4*)&op[k];
            const float4 w4 = *(const float4*)&wrow[k];
            po = fmaf(o4.x, w4.x, fmaf(o4.y, w4.y, fmaf(o4.z, w4.z, fmaf(o4.w, w4.w, po))));
        }
        scr[4096 + (half << 7) + z] = po;
    }
    __syncthreads();   // (F)
    if (tid < CZ)
        pre_out[(size_t)r * CZ + tid] = scr[4096 + tid] + scr[4096 + CZ + tid] + b_out[tid];
}

// ===================== Kernel B: broadcast pre over 1024 rows =====================
__launch_bounds__(256, 8)
__global__ void opm_bcast(const float* __restrict__ pre,
                          float* __restrict__ out)
{
    const int bid = blockIdx.x;
    const int r   = bid >> 3;                 // 0..1023
    const int jb  = bid & 7;                  // 128-row slab within the r-plane
    const int z4  = threadIdx.x & 31;         // which float4 of the 128-float row
    const int jo  = threadIdx.x >> 5;         // 0..7

    const f4v pv = *((const f4v*)(pre + (size_t)r * CZ) + z4);
    f4v* outp = (f4v*)out + ((size_t)r * NRES + (size_t)jb * 128) * (CZ / 4);
    for (int j0 = 0; j0 < 128; j0 += 8)
        __builtin_nontemporal_store(pv, &outp[(size_t)(j0 + jo) * (CZ / 4) + z4]);
}

extern "C" void kernel_launch(void* const* d_in, const int* in_sizes, int n_in,
                              void* d_out, int out_size, void* d_ws, size_t ws_size,
                              hipStream_t stream) {
    const float* msa   = (const float*)d_in[0];
    const float* nw    = (const float*)d_in[1];
    const float* nb    = (const float*)d_in[2];
    const float* w_ab  = (const float*)d_in[3];
    const float* b_ab  = (const float*)d_in[4];
    const float* w_out = (const float*)d_in[5];
    const float* b_out = (const float*)d_in[6];
    float* out = (float*)d_out;

    float* pre = (float*)d_ws;                           // [0, 131072) floats
    float* k12 = pre + (size_t)NRES * CZ;                // [131072, 131136)
    unsigned short* wb_su = (unsigned short*)(k12 + 64); // 16384 bf16 (32 KB), 16B-aligned

    opm_setup<<<1, 256, 0, stream>>>(nw, nb, w_ab, b_ab, k12, wb_su);
    opm_compute<<<NRES, 256, 0, stream>>>(msa, (const u32*)wb_su, k12, w_out, b_out, pre);
    opm_bcast<<<NRES * 8, 256, 0, stream>>>(pre, out);
}